// Round 4
// baseline (283.083 us; speedup 1.0000x reference)
//
#include <hip/hip_runtime.h>

#define NG 12
#define SD 64
#define ED 768
#define NB 262144
#define TPB 192          // 3 waves; thread t owns output cols [4t, 4t+4)
#define G   2048         // grid; ITERS grid-stride rows per block
#define ITERS (NB / G)   // 128

// M[g][o] = sum_s Wg[g][s] * Wagg[o][g*64+s];  Mb[g][o] = same with bg
__global__ void fge_pre1(const float* __restrict__ Wg,
                         const float* __restrict__ bg,
                         const float* __restrict__ Wagg,
                         float* __restrict__ M, float* __restrict__ Mb)
{
    int tid = blockIdx.x * blockDim.x + threadIdx.x;
    if (tid >= ED * NG) return;
    int o = tid / NG, g = tid % NG;   // 12 consecutive threads share one Wagg row
    const float* wrow = Wagg + (size_t)o * ED + g * SD;
    const float* wgp  = Wg + g * SD;
    const float* bgp  = bg + g * SD;
    float m = 0.f, mb = 0.f;
    #pragma unroll
    for (int s = 0; s < SD; ++s) {
        float w = wrow[s];
        m  += wgp[s] * w;
        mb += bgp[s] * w;
    }
    M [g * ED + o] = m;
    Mb[g * ED + o] = mb;
}

// c0[o] = bagg[o] + sum_g Mb[g][o]
__global__ void fge_pre2(const float* __restrict__ Mb,
                         const float* __restrict__ bagg,
                         float* __restrict__ c0)
{
    int o = blockIdx.x * blockDim.x + threadIdx.x;
    if (o >= ED) return;
    float s = bagg[o];
    #pragma unroll
    for (int g = 0; g < NG; ++g) s += Mb[g * ED + o];
    c0[o] = s;
}

// out[b][o] = c0[o] + sum_g counts[b][g] * M[g][o]
// Grid-stride writes (compact moving HBM window). ALL count loads hoisted to
// a one-shot staging phase -> LDS, so the main loop's only VMEM op is the
// store (never waited on); count reads are lgkmcnt-only LDS broadcasts.
__global__ __launch_bounds__(TPB) void fge_main(const int* __restrict__ counts,
                                                const float* __restrict__ M,
                                                const float* __restrict__ c0,
                                                float* __restrict__ out)
{
    __shared__ float scf[ITERS * NG];   // 6 KB: this block's 128 rows, as float
    const int t  = threadIdx.x;
    const int bb = blockIdx.x;

    // Stage: 128 rows x 3 int4 = 384 loads, thread t takes l = t, t+TPB.
    // All in flight at once -> one latency exposure for the whole kernel.
    #pragma unroll
    for (int k = 0; k < 2; ++k) {
        int l  = t + k * TPB;          // 0..383
        int ri = l / 3, p = l % 3;     // row index (grid-stride slot), 16B part
        int4 v = *reinterpret_cast<const int4*>(
                     counts + (size_t)(bb + ri * G) * NG + p * 4);
        *reinterpret_cast<float4*>(scf + ri * NG + p * 4) =
            make_float4((float)v.x, (float)v.y, (float)v.z, (float)v.w);
    }

    // Per-thread column slice of M and c0 in registers (reused for all rows)
    float m[NG][4];
    #pragma unroll
    for (int g = 0; g < NG; ++g) {
        float4 v = *reinterpret_cast<const float4*>(M + g * ED + t * 4);
        m[g][0] = v.x; m[g][1] = v.y; m[g][2] = v.z; m[g][3] = v.w;
    }
    const float4 base = *reinterpret_cast<const float4*>(c0 + t * 4);
    __syncthreads();

    const int o0 = t * 4;
    #pragma unroll 2
    for (int i = 0; i < ITERS; ++i) {
        // uniform-address LDS reads -> broadcast, conflict-free, lgkm-only
        const float4* cf4 = reinterpret_cast<const float4*>(scf + i * NG);
        float4 ca = cf4[0], cb = cf4[1], cc = cf4[2];
        float cf[NG] = { ca.x, ca.y, ca.z, ca.w,
                         cb.x, cb.y, cb.z, cb.w,
                         cc.x, cc.y, cc.z, cc.w };
        float4 acc = base;
        #pragma unroll
        for (int g = 0; g < NG; ++g) {
            acc.x = fmaf(cf[g], m[g][0], acc.x);
            acc.y = fmaf(cf[g], m[g][1], acc.y);
            acc.z = fmaf(cf[g], m[g][2], acc.z);
            acc.w = fmaf(cf[g], m[g][3], acc.w);
        }
        *reinterpret_cast<float4*>(out + (size_t)(bb + i * G) * ED + o0) = acc;
    }
}

extern "C" void kernel_launch(void* const* d_in, const int* in_sizes, int n_in,
                              void* d_out, int out_size, void* d_ws, size_t ws_size,
                              hipStream_t stream) {
    const int*   counts = (const int*)  d_in[0];
    const float* Wg     = (const float*)d_in[1];
    const float* bg     = (const float*)d_in[2];
    const float* Wagg   = (const float*)d_in[3];
    const float* bagg   = (const float*)d_in[4];
    float* out = (float*)d_out;

    float* M  = (float*)d_ws;            // 12*768 = 36 KB
    float* Mb = M  + NG * ED;            // 36 KB
    float* c0 = Mb + NG * ED;            // 3 KB

    fge_pre1<<<(ED * NG + 255) / 256, 256, 0, stream>>>(Wg, bg, Wagg, M, Mb);
    fge_pre2<<<(ED + 255) / 256, 256, 0, stream>>>(Mb, bagg, c0);
    fge_main<<<G, TPB, 0, stream>>>(counts, M, c0, out);
}

// Round 6
// 174.790 us; speedup vs baseline: 1.6196x; 1.6196x over previous
//
#include <hip/hip_runtime.h>

#define NG 12
#define SD 64
#define ED 768
#define NB 262144
#define TPB 192          // 3 waves; thread t owns output cols [4t, 4t+4)
#define G   2048         // grid size; 128 grid-stride iterations per block

typedef float f32x4 __attribute__((ext_vector_type(4)));  // native vec for nt-store

// M[g][o] = sum_s Wg[g][s] * Wagg[o][g*64+s];  Mb[g][o] = same with bg
__global__ void fge_pre1(const float* __restrict__ Wg,
                         const float* __restrict__ bg,
                         const float* __restrict__ Wagg,
                         float* __restrict__ M, float* __restrict__ Mb)
{
    int tid = blockIdx.x * blockDim.x + threadIdx.x;
    if (tid >= ED * NG) return;
    int o = tid / NG, g = tid % NG;   // 12 consecutive threads share one Wagg row
    const float* wrow = Wagg + (size_t)o * ED + g * SD;
    const float* wgp  = Wg + g * SD;
    const float* bgp  = bg + g * SD;
    float m = 0.f, mb = 0.f;
    #pragma unroll
    for (int s = 0; s < SD; ++s) {
        float w = wrow[s];
        m  += wgp[s] * w;
        mb += bgp[s] * w;
    }
    M [g * ED + o] = m;
    Mb[g * ED + o] = mb;
}

// c0[o] = bagg[o] + sum_g Mb[g][o]
__global__ void fge_pre2(const float* __restrict__ Mb,
                         const float* __restrict__ bagg,
                         float* __restrict__ c0)
{
    int o = blockIdx.x * blockDim.x + threadIdx.x;
    if (o >= ED) return;
    float s = bagg[o];
    #pragma unroll
    for (int g = 0; g < NG; ++g) s += Mb[g * ED + o];
    c0[o] = s;
}

__device__ __forceinline__ void row_compute(int4 x, int4 y, int4 z,
                                            const float (&m)[NG][4],
                                            float4 base, float* __restrict__ dst)
{
    float cf[NG] = { (float)x.x, (float)x.y, (float)x.z, (float)x.w,
                     (float)y.x, (float)y.y, (float)y.z, (float)y.w,
                     (float)z.x, (float)z.y, (float)z.z, (float)z.w };
    float4 acc = base;
    #pragma unroll
    for (int g = 0; g < NG; ++g) {
        acc.x = fmaf(cf[g], m[g][0], acc.x);
        acc.y = fmaf(cf[g], m[g][1], acc.y);
        acc.z = fmaf(cf[g], m[g][2], acc.z);
        acc.w = fmaf(cf[g], m[g][3], acc.w);
    }
    // Write-once streaming output: nontemporal (LLC no-allocate) store keeps
    // the L2 clean for the count-read stream and avoids dirty-line churn.
    f32x4 v = { acc.x, acc.y, acc.z, acc.w };
    __builtin_nontemporal_store(v, reinterpret_cast<f32x4*>(dst));
}

// out[b][o] = c0[o] + sum_g counts[b][g] * M[g][o]
// Grid-stride (compact moving write window) + 2-deep scalar count prefetch.
__global__ __launch_bounds__(TPB) void fge_main(const int* __restrict__ counts,
                                                const float* __restrict__ M,
                                                const float* __restrict__ c0,
                                                float* __restrict__ out)
{
    const int t  = threadIdx.x;
    const int o0 = t * 4;

    float m[NG][4];
    #pragma unroll
    for (int g = 0; g < NG; ++g) {
        float4 v = *reinterpret_cast<const float4*>(M + g * ED + o0);
        m[g][0] = v.x; m[g][1] = v.y; m[g][2] = v.z; m[g][3] = v.w;
    }
    const float4 base = *reinterpret_cast<const float4*>(c0 + o0);

    const int4* cp = reinterpret_cast<const int4*>(counts);  // 3 int4 per row

    int b = blockIdx.x;
    // prime 2-deep prefetch: rows b and b+G (uniform addr -> s_load_dwordx4)
    int4 A0 = cp[b * 3], A1 = cp[b * 3 + 1], A2 = cp[b * 3 + 2];
    int nb1 = b + G;
    int4 B0 = cp[nb1 * 3], B1 = cp[nb1 * 3 + 1], B2 = cp[nb1 * 3 + 2];

    #pragma unroll 1
    for (int i = 0; i < NB / G; i += 2) {
        row_compute(A0, A1, A2, m, base, out + (size_t)b * ED + o0);
        int pa = b + 2 * G; pa = pa < NB ? pa : NB - 1;      // clamp tail
        A0 = cp[pa * 3]; A1 = cp[pa * 3 + 1]; A2 = cp[pa * 3 + 2];

        row_compute(B0, B1, B2, m, base, out + (size_t)(b + G) * ED + o0);
        int pb = b + 3 * G; pb = pb < NB ? pb : NB - 1;
        B0 = cp[pb * 3]; B1 = cp[pb * 3 + 1]; B2 = cp[pb * 3 + 2];

        b += 2 * G;
    }
}

extern "C" void kernel_launch(void* const* d_in, const int* in_sizes, int n_in,
                              void* d_out, int out_size, void* d_ws, size_t ws_size,
                              hipStream_t stream) {
    const int*   counts = (const int*)  d_in[0];
    const float* Wg     = (const float*)d_in[1];
    const float* bg     = (const float*)d_in[2];
    const float* Wagg   = (const float*)d_in[3];
    const float* bagg   = (const float*)d_in[4];
    float* out = (float*)d_out;

    float* M  = (float*)d_ws;            // 12*768 = 36 KB
    float* Mb = M  + NG * ED;            // 36 KB
    float* c0 = Mb + NG * ED;            // 3 KB

    fge_pre1<<<(ED * NG + 255) / 256, 256, 0, stream>>>(Wg, bg, Wagg, M, Mb);
    fge_pre2<<<(ED + 255) / 256, 256, 0, stream>>>(Mb, bagg, c0);
    fge_main<<<G, TPB, 0, stream>>>(counts, M, c0, out);
}

// Round 7
// 168.126 us; speedup vs baseline: 1.6838x; 1.0396x over previous
//
#include <hip/hip_runtime.h>

#define NG 12
#define SD 64
#define ED 768
#define NB 262144
#define TPB 192          // 3 waves; thread t owns output cols [4t, 4t+4)
#define G   4096         // grid size; ITERS grid-stride iterations per block
#define ITERS (NB / G)   // 64
#define PF  4            // prefetch depth (rows ahead, SGPR-resident)

typedef float f32x4 __attribute__((ext_vector_type(4)));  // native vec for nt-store

// M[g][o] = sum_s Wg[g][s] * Wagg[o][g*64+s];  Mb[g][o] = same with bg
__global__ void fge_pre1(const float* __restrict__ Wg,
                         const float* __restrict__ bg,
                         const float* __restrict__ Wagg,
                         float* __restrict__ M, float* __restrict__ Mb)
{
    int tid = blockIdx.x * blockDim.x + threadIdx.x;
    if (tid >= ED * NG) return;
    int o = tid / NG, g = tid % NG;   // 12 consecutive threads share one Wagg row
    const float* wrow = Wagg + (size_t)o * ED + g * SD;
    const float* wgp  = Wg + g * SD;
    const float* bgp  = bg + g * SD;
    float m = 0.f, mb = 0.f;
    #pragma unroll
    for (int s = 0; s < SD; ++s) {
        float w = wrow[s];
        m  += wgp[s] * w;
        mb += bgp[s] * w;
    }
    M [g * ED + o] = m;
    Mb[g * ED + o] = mb;
}

// c0[o] = bagg[o] + sum_g Mb[g][o]
__global__ void fge_pre2(const float* __restrict__ Mb,
                         const float* __restrict__ bagg,
                         float* __restrict__ c0)
{
    int o = blockIdx.x * blockDim.x + threadIdx.x;
    if (o >= ED) return;
    float s = bagg[o];
    #pragma unroll
    for (int g = 0; g < NG; ++g) s += Mb[g * ED + o];
    c0[o] = s;
}

__device__ __forceinline__ void row_compute(int4 x, int4 y, int4 z,
                                            const float (&m)[NG][4],
                                            float4 base, float* __restrict__ dst)
{
    float cf[NG] = { (float)x.x, (float)x.y, (float)x.z, (float)x.w,
                     (float)y.x, (float)y.y, (float)y.z, (float)y.w,
                     (float)z.x, (float)z.y, (float)z.z, (float)z.w };
    float4 acc = base;
    #pragma unroll
    for (int g = 0; g < NG; ++g) {
        acc.x = fmaf(cf[g], m[g][0], acc.x);
        acc.y = fmaf(cf[g], m[g][1], acc.y);
        acc.z = fmaf(cf[g], m[g][2], acc.z);
        acc.w = fmaf(cf[g], m[g][3], acc.w);
    }
    // Write-once streaming output: nontemporal (LLC no-allocate) store keeps
    // the L2 clean and avoids dirty-line churn (round 6: -25%).
    f32x4 v = { acc.x, acc.y, acc.z, acc.w };
    __builtin_nontemporal_store(v, reinterpret_cast<f32x4*>(dst));
}

// out[b][o] = c0[o] + sum_g counts[b][g] * M[g][o]
// Grid-stride (compact moving write window) + PF-deep scalar count prefetch.
__global__ __launch_bounds__(TPB) void fge_main(const int* __restrict__ counts,
                                                const float* __restrict__ M,
                                                const float* __restrict__ c0,
                                                float* __restrict__ out)
{
    const int t  = threadIdx.x;
    const int o0 = t * 4;

    float m[NG][4];
    #pragma unroll
    for (int g = 0; g < NG; ++g) {
        float4 v = *reinterpret_cast<const float4*>(M + g * ED + o0);
        m[g][0] = v.x; m[g][1] = v.y; m[g][2] = v.z; m[g][3] = v.w;
    }
    const float4 base = *reinterpret_cast<const float4*>(c0 + o0);

    const int4* cp = reinterpret_cast<const int4*>(counts);  // 3 int4 per row

    // Rotating PF-deep prefetch buffer (uniform addr -> s_load_dwordx4 x3)
    int4 P[PF][3];
    #pragma unroll
    for (int k = 0; k < PF; ++k) {
        int r = blockIdx.x + k * G;
        P[k][0] = cp[r * 3]; P[k][1] = cp[r * 3 + 1]; P[k][2] = cp[r * 3 + 2];
    }

    int b = blockIdx.x;
    #pragma unroll 1
    for (int i = 0; i < ITERS; i += PF) {
        #pragma unroll
        for (int k = 0; k < PF; ++k) {
            row_compute(P[k][0], P[k][1], P[k][2], m, base,
                        out + (size_t)(b + k * G) * ED + o0);
            int pr = b + (k + PF) * G; pr = pr < NB ? pr : NB - 1;  // clamp tail
            P[k][0] = cp[pr * 3]; P[k][1] = cp[pr * 3 + 1]; P[k][2] = cp[pr * 3 + 2];
        }
        b += PF * G;
    }
}

extern "C" void kernel_launch(void* const* d_in, const int* in_sizes, int n_in,
                              void* d_out, int out_size, void* d_ws, size_t ws_size,
                              hipStream_t stream) {
    const int*   counts = (const int*)  d_in[0];
    const float* Wg     = (const float*)d_in[1];
    const float* bg     = (const float*)d_in[2];
    const float* Wagg   = (const float*)d_in[3];
    const float* bagg   = (const float*)d_in[4];
    float* out = (float*)d_out;

    float* M  = (float*)d_ws;            // 12*768 = 36 KB
    float* Mb = M  + NG * ED;            // 36 KB
    float* c0 = Mb + NG * ED;            // 3 KB

    fge_pre1<<<(ED * NG + 255) / 256, 256, 0, stream>>>(Wg, bg, Wagg, M, Mb);
    fge_pre2<<<(ED + 255) / 256, 256, 0, stream>>>(Mb, bagg, c0);
    fge_main<<<G, TPB, 0, stream>>>(counts, M, c0, out);
}